// Round 11
// baseline (56.246 us; speedup 1.0000x reference)
//
#include <hip/hip_runtime.h>
#include <stdint.h>

#define HW   4096      // 64*64 spatial per batch
#define NEMB 1024

typedef float        f32x4  __attribute__((ext_vector_type(4)));
typedef short        h16x8  __attribute__((ext_vector_type(8)));
typedef unsigned int u32x4  __attribute__((ext_vector_type(4)));

// pack 2 fp32 -> 2 fp16 (RTZ) in one u32 (lo = first operand)
#define CVTPKH(D, LO, HI) asm("v_cvt_pkrtz_f16_f32 %0, %1, %2" : "=v"(D) : "v"(LO), "v"(HI))

// direct global->LDS DMA, 16B per lane (lane-linear dest)
__device__ __forceinline__ void gload_lds16(const float* g, float* l) {
    __builtin_amdgcn_global_load_lds(
        (const __attribute__((address_space(1))) void*)(uintptr_t)g,
        (__attribute__((address_space(3))) void*)(uintptr_t)l, 16, 0, 0);
}

// ---------------- init: zero counts/errsum/flag, ens1[k]=1+||e||^2, f16 codebook --
// 16 blocks x 128: thread = half-row. embh: u32[1024][32]; u32 4c+p of row k =
// f16 pair (e[8c+2p], e[8c+2p+1]).
__global__ __launch_bounds__(128) void vq_init(const float* __restrict__ emb,
                                               unsigned int* __restrict__ counts,
                                               float* __restrict__ errsum,
                                               float* __restrict__ ens1,
                                               unsigned int* __restrict__ embh,
                                               unsigned int* __restrict__ flag) {
    const int gid  = blockIdx.x * 128 + threadIdx.x;   // 0..2047
    const int k    = gid >> 1;
    const int half = gid & 1;
    if (half == 0) counts[k] = 0u;
    if (gid == 0) { *errsum = 0.0f; *flag = 0u; }
    const float* e = emb + k * 64 + half * 32;
    unsigned int* dst = embh + k * 32 + half * 16;
    float nrm = 0.0f;
    #pragma unroll
    for (int c = 0; c < 4; ++c) {
        f32x4 v0 = *(const f32x4*)(e + c * 8);
        f32x4 v1 = *(const f32x4*)(e + c * 8 + 4);
        nrm += v0.x*v0.x + v0.y*v0.y + v0.z*v0.z + v0.w*v0.w
             + v1.x*v1.x + v1.y*v1.y + v1.z*v1.z + v1.w*v1.w;
        u32x4 w;
        CVTPKH(w.x, v0.x, v0.y); CVTPKH(w.y, v0.z, v0.w);
        CVTPKH(w.z, v1.x, v1.y); CVTPKH(w.w, v1.z, v1.w);
        *(u32x4*)&dst[c * 4] = w;
    }
    float o = __shfl_xor(nrm, 1, 64);
    if (half == 0) ens1[k] = 1.0f + (nrm + o);   // order arbitrary: screen-only
}

// ---------------- fused main: screen + argmin + epilogue + (last block) scalars ---
// grid 512 x 512 (2 blocks/CU). Block: 128 samples. Wave wv owns embs
// wv*128..+127 as persistent B-frags; loops 8 sample-tiles of 16.
__global__ __launch_bounds__(512, 4)
void vq_main(const float* __restrict__ z, const float* __restrict__ emb,
             const float* __restrict__ ens1, const unsigned int* __restrict__ embh,
             float* __restrict__ out, unsigned int* __restrict__ counts,
             float* __restrict__ errsum, unsigned int* __restrict__ flag)
{
    __shared__ __attribute__((aligned(16))) float z_lds[64 * 128];     // fp32 [d][x]
    __shared__ __attribute__((aligned(16))) unsigned int zh[128 * 32]; // f16 pairs [x][slot]
    __shared__ unsigned int kd[8][128];
    __shared__ int   idx_sh[128];
    __shared__ float errw[8];
    __shared__ unsigned int rank_s;

    const int t   = threadIdx.x;
    const int n0  = blockIdx.x * 128;
    const int bb  = n0 >> 12;
    const int hw0 = n0 & 4095;
    const float* zb = z + bb * (64 * HW) + hw0;

    // ---- issue z DMA first (latency hides under B/en loads) ----
    #pragma unroll
    for (int it = 0; it < 4; ++it) {
        const int p = it * 512 + t;
        gload_lds16(zb + (p >> 5) * HW + (p & 31) * 4, z_lds + p * 4);
    }

    const int l   = t & 63;
    const int wv  = t >> 6;
    const int col = l & 15;
    const int bg  = l >> 4;

    // ---- persistent B-frags + en from global (independent of LDS) ----
    u32x4 bw0[8], bw1[8];
    {
        const unsigned int* ebase = embh + (wv * 128 + col) * 32 + bg * 4;
        #pragma unroll
        for (int g = 0; g < 8; ++g) {
            bw0[g] = *(const u32x4*)(ebase + g * 512);
            bw1[g] = *(const u32x4*)(ebase + g * 512 + 16);
        }
    }
    float en[8];
    #pragma unroll
    for (int g = 0; g < 8; ++g) en[g] = ens1[wv * 128 + g * 16 + col];

    __syncthreads();   // z_lds ready

    // ---- zh: f16-packed z, slot s of row x holds chunk s^(x&7) ----
    {
        const int x = t & 127;
        #pragma unroll
        for (int ss = 0; ss < 2; ++ss) {
            const int s = (x + (t >> 7) * 2 + ss) & 7;
            const int c = s ^ (x & 7);
            u32x4 w;
            CVTPKH(w.x, z_lds[(8*c + 0) * 128 + x], z_lds[(8*c + 1) * 128 + x]);
            CVTPKH(w.y, z_lds[(8*c + 2) * 128 + x], z_lds[(8*c + 3) * 128 + x]);
            CVTPKH(w.z, z_lds[(8*c + 4) * 128 + x], z_lds[(8*c + 5) * 128 + x]);
            CVTPKH(w.w, z_lds[(8*c + 6) * 128 + x], z_lds[(8*c + 7) * 128 + x]);
            *(u32x4*)&zh[x * 32 + s * 4] = w;
        }
    }
    __syncthreads();

    // ---- 8 sample-tiles: 16 independent MFMAs each, keys, 4-round reduce ----
    const unsigned int lkc = (unsigned int)col;
    #pragma unroll 1
    for (int st = 0; st < 8; ++st) {
        const int xs = st * 16 + col;
        const int sA = bg ^ (col & 7);
        u32x4 wa = *(const u32x4*)&zh[xs * 32 + sA * 4];
        u32x4 wb = *(const u32x4*)&zh[xs * 32 + (sA ^ 4) * 4];
        h16x8 a0 = __builtin_bit_cast(h16x8, wa);
        h16x8 a1 = __builtin_bit_cast(h16x8, wb);

        unsigned int k0 = ~0u, k1 = ~0u, k2 = ~0u, k3 = ~0u;
        #pragma unroll
        for (int g = 0; g < 8; ++g) {
            f32x4 cc = {0.0f, 0.0f, 0.0f, 0.0f};
            f32x4 cd = {0.0f, 0.0f, 0.0f, 0.0f};
            cc = __builtin_amdgcn_mfma_f32_16x16x32_f16(a0, __builtin_bit_cast(h16x8, bw0[g]), cc, 0, 0, 0);
            cd = __builtin_amdgcn_mfma_f32_16x16x32_f16(a1, __builtin_bit_cast(h16x8, bw1[g]), cd, 0, 0, 0);
            const unsigned int lk = (unsigned int)(g << 4) | lkc;
            float s0 = fmaf(-2.0f, cc[0] + cd[0], en[g]);
            float s1 = fmaf(-2.0f, cc[1] + cd[1], en[g]);
            float s2 = fmaf(-2.0f, cc[2] + cd[2], en[g]);
            float s3 = fmaf(-2.0f, cc[3] + cd[3], en[g]);
            unsigned int q0 = (__builtin_bit_cast(unsigned int, s0) & ~127u) | lk;
            unsigned int q1 = (__builtin_bit_cast(unsigned int, s1) & ~127u) | lk;
            unsigned int q2 = (__builtin_bit_cast(unsigned int, s2) & ~127u) | lk;
            unsigned int q3 = (__builtin_bit_cast(unsigned int, s3) & ~127u) | lk;
            k0 = k0 < q0 ? k0 : q0;  k1 = k1 < q1 ? k1 : q1;
            k2 = k2 < q2 ? k2 : q2;  k3 = k3 < q3 ? k3 : q3;
        }
        #pragma unroll
        for (int mk = 1; mk <= 8; mk <<= 1) {
            unsigned int o0 = (unsigned int)__shfl_xor((int)k0, mk, 64);
            unsigned int o1 = (unsigned int)__shfl_xor((int)k1, mk, 64);
            unsigned int o2 = (unsigned int)__shfl_xor((int)k2, mk, 64);
            unsigned int o3 = (unsigned int)__shfl_xor((int)k3, mk, 64);
            k0 = k0 < o0 ? k0 : o0;  k1 = k1 < o1 ? k1 : o1;
            k2 = k2 < o2 ? k2 : o2;  k3 = k3 < o3 ? k3 : o3;
        }
        if (col == 0) {
            u32x4 kv = {k0, k1, k2, k3};
            *(u32x4*)&kd[wv][st * 16 + bg * 4] = kv;
        }
    }
    __syncthreads();

    // ---- cross-wave argmin (8 candidates/sample) + histogram ----
    if (t < 128) {
        unsigned int kw = kd[0][t];
        unsigned int bv = kw & ~127u;
        int bk = (int)(kw & 127u);
        #pragma unroll
        for (int w = 1; w < 8; ++w) {
            kw = kd[w][t];
            unsigned int vw = kw & ~127u;
            int kk = w * 128 + (int)(kw & 127u);
            if (vw < bv || (vw == bv && kk < bk)) { bv = vw; bk = kk; }
        }
        idx_sh[t] = bk;
        atomicAdd(&counts[bk], 1u);
    }
    __syncthreads();

    // ---- epilogue: out = z + (e - z) exact; per-wave error reduce ----
    float part = 0.0f;
    {
        const int x  = t & 127;
        const int cg = t >> 7;
        const int idx = idx_sh[x];
        const float* er = emb + idx * 64;
        float* ob = out + bb * (64 * HW) + hw0 + x;
        #pragma unroll
        for (int cq = 0; cq < 4; ++cq) {
            const int c = cg * 16 + cq * 4;
            f32x4 e4 = *(const f32x4*)&er[c];
            float z0 = z_lds[(c+0) * 128 + x];
            float z1 = z_lds[(c+1) * 128 + x];
            float z2 = z_lds[(c+2) * 128 + x];
            float z3 = z_lds[(c+3) * 128 + x];
            ob[(c+0) * HW] = z0 + (e4.x - z0);
            ob[(c+1) * HW] = z1 + (e4.y - z1);
            ob[(c+2) * HW] = z2 + (e4.z - z2);
            ob[(c+3) * HW] = z3 + (e4.w - z3);
            float d0 = z0 - e4.x, d1 = z1 - e4.y, d2 = z2 - e4.z, d3 = z3 - e4.w;
            part = fmaf(d0, d0, part); part = fmaf(d1, d1, part);
            part = fmaf(d2, d2, part); part = fmaf(d3, d3, part);
        }
    }
    {
        float s = part;
        #pragma unroll
        for (int off = 32; off >= 1; off >>= 1) s += __shfl_down(s, off, 64);
        if (l == 0) errw[wv] = s;
    }
    __syncthreads();
    if (t == 0) {
        float es = ((errw[0]+errw[1]) + (errw[2]+errw[3]))
                 + ((errw[4]+errw[5]) + (errw[6]+errw[7]));
        atomicAdd(errsum, es);
        __threadfence();                       // counts/errsum visible before flag
        rank_s = atomicAdd(flag, 1u);
    }
    __syncthreads();

    // ---- last block computes the scalars (replaces vq_fin) ----
    if (rank_s == 511u) {
        __threadfence();
        float s = 0.0f;
        #pragma unroll
        for (int k2 = t; k2 < NEMB; k2 += 512) {
            unsigned int cv = atomicAdd(&counts[k2], 0u);   // coherent read
            float p = (float)cv * (1.0f / 65536.0f);
            s += p * logf(p + 1e-10f);
        }
        #pragma unroll
        for (int off = 32; off >= 1; off >>= 1) s += __shfl_down(s, off, 64);
        if (l == 0) errw[wv] = s;
        __syncthreads();
        if (t == 0) {
            float tot = ((errw[0]+errw[1]) + (errw[2]+errw[3]))
                      + ((errw[4]+errw[5]) + (errw[6]+errw[7]));
            float es = atomicAdd(errsum, 0.0f);             // coherent read
            float* scal = out + 4194304;
            scal[0] = 1.25f * (es * (1.0f / 4194304.0f));   // loss
            scal[1] = expf(-tot);                           // perplexity
            scal[2] = es * (1.0f / 65536.0f);               // avg_error
        }
    }
}

extern "C" void kernel_launch(void* const* d_in, const int* in_sizes, int n_in,
                              void* d_out, int out_size, void* d_ws, size_t ws_size,
                              hipStream_t stream) {
    const float* z   = (const float*)d_in[0];
    const float* emb = (const float*)d_in[1];
    float* out = (float*)d_out;
    unsigned int* counts = (unsigned int*)d_ws;
    float* errsum = (float*)((char*)d_ws + 4096);
    unsigned int* flag = (unsigned int*)((char*)d_ws + 4160);
    float* ens1   = (float*)((char*)d_ws + 8192);
    unsigned int* embh = (unsigned int*)((char*)d_ws + 16384);

    vq_init<<<16, 128, 0, stream>>>(emb, counts, errsum, ens1, embh, flag);
    vq_main<<<512, 512, 0, stream>>>(z, emb, ens1, embh, out, counts, errsum, flag);
}